// Round 10
// baseline (5184.933 us; speedup 1.0000x reference)
//
#include <hip/hip_runtime.h>
#include <array>

#define CPG 8
#define NGRP 32
#define NB 16
#define HW 3136
#define HU 784       // float4 units per channel image
#define N2 36
#define N3 120

typedef float vfloat4 __attribute__((ext_vector_type(4)));

__host__ __device__ constexpr int idx2(int i, int j) {
    return i * CPG - i * (i - 1) / 2 + (j - i);
}
__host__ __device__ constexpr int idx3(int a, int b, int c) {
    int base = 0;
    for (int t = 0; t < a; ++t) { int m = CPG - t; base += m * (m + 1) / 2; }
    for (int t = a; t < b; ++t) base += CPG - t;
    return base + (c - b);
}

__device__ inline vfloat4 splat4(float s) { return (vfloat4){s, s, s, s}; }

// Flat feature schedule (validated in R8: full constant-folding, no perf loss).
// pi>=0 && pj>=0 : p = xv[pi]*xv[pj], t = p          (new degree-2 pair)
// pi>=0 && pj<0  : t = xv[pi]                        (degree-1)
// pi<0           : t = xv[a]*p                       (degree-3, reuses p)
struct Feat { short row; signed char pi, pj, a; };

constexpr std::array<Feat, 164> make_feats() {
    std::array<Feat, 164> t{};
    int n = 0;
    for (int k = 0; k < CPG; ++k)
        t[n++] = Feat{(short)k, (signed char)k, (signed char)-1, (signed char)-1};
    for (int i = 0; i < CPG; ++i)
        for (int j = i; j < CPG; ++j) {
            t[n++] = Feat{(short)(8 + idx2(i, j)), (signed char)i, (signed char)j,
                          (signed char)-1};
            for (int a = 0; a <= i; ++a)
                t[n++] = Feat{(short)(44 + idx3(a, i, j)), (signed char)-1,
                              (signed char)-1, (signed char)a};
        }
    return t;
}

// per-feature fence: bounds in-flight weight regs to the rolling pair (8 regs)
#define FENCE() __builtin_amdgcn_sched_barrier(0)

// DS-halved layout: each lane owns 2 pixel-quads x 4 outputs; one wave-uniform
// ds_read_b128 per feature (16B = this wave's output-half) feeds 8 fmacs.
// 164 reads per 8 out-quads/lane vs 328 in the R3 layout.
// Register budget: hipcc targets 2x the declared min-waves (measured R4-R9:
// cap = 512/(2*arg)). Live set ~122 regs -> arg 2 grants cap 128.
__global__ __launch_bounds__(256, 2) void hoaf_kernel(
    const float* __restrict__ x,
    const float* __restrict__ w1, const float* __restrict__ b1,
    const float* __restrict__ w2, const float* __restrict__ b2,
    const float* __restrict__ w3, const float* __restrict__ b3,
    float* __restrict__ out)
{
    // wt[f][o]: f 0-7 deg1, 8-43 deg2, 44-163 deg3, 164 = summed bias
    __shared__ __align__(16) float wt[165][8];

    const int tid   = threadIdx.x;
    const int g     = blockIdx.x;   // block-uniform group
    const int b     = blockIdx.y;
    const int chunk = blockIdx.z;   // 0..3; chunk 3 is a runt

    for (int idx = tid; idx < 165 * 8; idx += 256) {
        const int f = idx >> 3, o = idx & 7;
        const int ch = g * CPG + o;
        float v;
        if (f < 8)        v = w1[ch * CPG + f];
        else if (f < 44)  v = w2[ch * N2 + (f - 8)];
        else if (f < 164) v = w3[ch * N3 + (f - 44)];
        else              v = b1[ch] + b2[ch] + b3[ch];
        wt[f][o] = v;
    }
    __syncthreads();

    // wave -> (output-half, quad-set); lane -> 2 pixel-quads (8 pixels)
    const int wave = tid >> 6;
    const int lane = tid & 63;
    const int half = wave & 1;    // 0: outputs 0-3, 1: outputs 4-7
    const int qset = wave >> 1;   // 0,1
    const int h4   = half * 4;

    const int q0 = chunk * 256 + qset * 128 + lane;
    const int q1 = q0 + 64;
    if (q0 >= HU) return;
    const bool has1 = (q1 < HU);
    const int  q1c  = has1 ? q1 : q0;   // clamped for loads

    const size_t base = ((size_t)(b * NGRP + g) * CPG) * HW;
    const vfloat4* x4 = (const vfloat4*)(x + base);
    vfloat4*       o4 = (vfloat4*)(out + base);

    vfloat4 xlo[CPG], xhi[CPG];
#pragma unroll
    for (int c = 0; c < CPG; ++c) {
        xlo[c] = x4[(size_t)c * HU + q0];
        xhi[c] = x4[(size_t)c * HU + q1c];
    }

    vfloat4 acc0[4], acc1[4];
#pragma unroll
    for (int o = 0; o < 4; ++o) {
        acc0[o] = splat4(wt[164][h4 + o]);
        acc1[o] = acc0[o];
    }

    constexpr auto FT = make_feats();

#define LDW(row) (*reinterpret_cast<const vfloat4*>(&wt[(row)][h4]))

    // distance-1 rolling weight pipeline: read n+1, consume n
    vfloat4 wcur = LDW(FT[0].row);
    vfloat4 plo = splat4(0.0f), phi = splat4(0.0f);

#pragma unroll
    for (int n = 0; n < 164; ++n) {
        const int nxrow = (n + 1 < 164) ? FT[n + 1].row : 164;  // bias row: benign
        const vfloat4 wnext = LDW(nxrow);

        vfloat4 tlo, thi;
        if (FT[n].pi >= 0 && FT[n].pj >= 0) {        // new degree-2 pair
            plo = xlo[FT[n].pi] * xlo[FT[n].pj];
            phi = xhi[FT[n].pi] * xhi[FT[n].pj];
            tlo = plo; thi = phi;
        } else if (FT[n].pi >= 0) {                  // degree-1
            tlo = xlo[FT[n].pi]; thi = xhi[FT[n].pi];
        } else {                                     // degree-3, reuse p
            tlo = xlo[FT[n].a] * plo;
            thi = xhi[FT[n].a] * phi;
        }

        acc0[0] += wcur.x * tlo; acc1[0] += wcur.x * thi;
        acc0[1] += wcur.y * tlo; acc1[1] += wcur.y * thi;
        acc0[2] += wcur.z * tlo; acc1[2] += wcur.z * thi;
        acc0[3] += wcur.w * tlo; acc1[3] += wcur.w * thi;

        wcur = wnext;
        FENCE();
    }
#undef LDW

#pragma unroll
    for (int o = 0; o < 4; ++o) {
        const size_t row = (size_t)(h4 + o) * HU;
        o4[row + q0] = acc0[o];
        if (has1) o4[row + q1] = acc1[o];
    }
}

extern "C" void kernel_launch(void* const* d_in, const int* in_sizes, int n_in,
                              void* d_out, int out_size, void* d_ws, size_t ws_size,
                              hipStream_t stream) {
    const float* x  = (const float*)d_in[0];
    const float* w1 = (const float*)d_in[1];
    const float* b1 = (const float*)d_in[2];
    const float* w2 = (const float*)d_in[3];
    const float* b2 = (const float*)d_in[4];
    const float* w3 = (const float*)d_in[5];
    const float* b3 = (const float*)d_in[6];
    float* out = (float*)d_out;

    dim3 grid(NGRP, NB, 4);   // (group, batch, pixel-chunk) — chunk slowest
    dim3 block(256);
    hoaf_kernel<<<grid, block, 0, stream>>>(x, w1, b1, w2, b2, w3, b3, out);
}

// Round 11
// 147.077 us; speedup vs baseline: 35.2532x; 35.2532x over previous
//
#include <hip/hip_runtime.h>

#define CPG 8
#define NGRP 32
#define NB 16
#define HW 3136
#define HU 784       // float4 units per channel image
#define N2 36
#define N3 120
#define NF 165       // 164 poly features + 1 summed-bias row
#define WSTRIDE (NF * CPG)   // 1320 floats per group in ws

typedef float vfloat4 __attribute__((ext_vector_type(4)));

__host__ __device__ constexpr int idx2(int i, int j) {
    return i * CPG - i * (i - 1) / 2 + (j - i);
}
__host__ __device__ constexpr int idx3(int a, int b, int c) {
    int base = 0;
    for (int t = 0; t < a; ++t) { int m = CPG - t; base += m * (m + 1) / 2; }
    for (int t = a; t < b; ++t) base += CPG - t;
    return base + (c - b);
}

__device__ inline vfloat4 splat4(float s) { return (vfloat4){s, s, s, s}; }

// ---------------------------------------------------------------------------
// prep: transpose weights to ws[g][f][o] (f-major, 8 contiguous outputs per
// feature, 32B-aligned) so the main kernel's weight reads are single
// s_load_dwordx8 per feature. f 0-7: deg1, 8-43: deg2, 44-163: deg3, 164: bias
// ---------------------------------------------------------------------------
__global__ __launch_bounds__(256) void prep_weights(
    const float* __restrict__ w1, const float* __restrict__ b1,
    const float* __restrict__ w2, const float* __restrict__ b2,
    const float* __restrict__ w3, const float* __restrict__ b3,
    float* __restrict__ ws)
{
    const int g = blockIdx.x;
    for (int idx = threadIdx.x; idx < WSTRIDE; idx += 256) {
        const int f = idx >> 3, o = idx & 7;
        const int ch = g * CPG + o;
        float v;
        if (f < 8)        v = w1[ch * CPG + f];
        else if (f < 44)  v = w2[ch * N2 + (f - 8)];
        else if (f < 164) v = w3[ch * N3 + (f - 44)];
        else              v = b1[ch] + b2[ch] + b3[ch];
        ws[g * WSTRIDE + idx] = v;
    }
}

// weights land in SGPRs (uniform address, contiguous dwordx8); fmac takes the
// scalar operand directly. No LDS, no fences — SMEM prefetch hoisting is the
// point, and the SGPR file bounds it.
#define ACCUMS(F, T) do {                                                    \
    const float w0 = wp[(F) * 8 + 0], w1_ = wp[(F) * 8 + 1];                 \
    const float w2_ = wp[(F) * 8 + 2], w3_ = wp[(F) * 8 + 3];                \
    const float w4_ = wp[(F) * 8 + 4], w5_ = wp[(F) * 8 + 5];                \
    const float w6_ = wp[(F) * 8 + 6], w7_ = wp[(F) * 8 + 7];                \
    acc[0] += w0  * (T); acc[1] += w1_ * (T);                                \
    acc[2] += w2_ * (T); acc[3] += w3_ * (T);                                \
    acc[4] += w4_ * (T); acc[5] += w5_ * (T);                                \
    acc[6] += w6_ * (T); acc[7] += w7_ * (T);                                \
} while (0)

// VGPR live set ~78 (xv 32 + acc 32 + temps; weights are SGPR) -> arg 2's
// 128-reg cap has wide margin; HW residency then follows usage (~6 blocks/CU).
__global__ __launch_bounds__(256, 2) void hoaf_sload(
    const float* __restrict__ x,
    const float* __restrict__ ws,
    float* __restrict__ out)
{
    const int tid   = threadIdx.x;
    const int g     = blockIdx.x;   // block-uniform group
    const int b     = blockIdx.y;
    const int chunk = blockIdx.z;   // 0..3; chunk 3 is a 16-unit runt

    const int q = tid + chunk * 256;   // one float4 body per thread
    if (q >= HU) return;

    const float* __restrict__ wp = ws + g * WSTRIDE;  // uniform -> s_load

    const size_t base = ((size_t)(b * NGRP + g) * CPG) * HW;
    const vfloat4* x4 = (const vfloat4*)(x + base);
    vfloat4*       o4 = (vfloat4*)(out + base);

    vfloat4 xv[CPG];
#pragma unroll
    for (int c = 0; c < CPG; ++c) xv[c] = x4[(size_t)c * HU + q];

    vfloat4 acc[CPG];
#pragma unroll
    for (int o = 0; o < CPG; ++o) acc[o] = splat4(wp[164 * 8 + o]);

    // degree 1
#pragma unroll
    for (int k = 0; k < CPG; ++k) ACCUMS(k, xv[k]);

    // degree 2 & 3: pair product (i<=j) feeds triples (a<=i<=j)
#pragma unroll
    for (int i = 0; i < CPG; ++i) {
#pragma unroll
        for (int j = i; j < CPG; ++j) {
            const vfloat4 p = xv[i] * xv[j];
            ACCUMS(8 + idx2(i, j), p);
#pragma unroll
            for (int a = 0; a <= i; ++a) {
                const vfloat4 t = xv[a] * p;
                ACCUMS(44 + idx3(a, i, j), t);
            }
        }
    }

#pragma unroll
    for (int o = 0; o < CPG; ++o) o4[(size_t)o * HU + q] = acc[o];
}

// ---------------------------------------------------------------------------
// Fallback (workspace too small): R3 kernel verbatim — LDS broadcast weights,
// 68.5 us measured, known-good.
// ---------------------------------------------------------------------------
#define ACCUM(F, T) do {                                                       \
    const vfloat4 wa = *reinterpret_cast<const vfloat4*>(&wt[(F)][0]);         \
    const vfloat4 wb = *reinterpret_cast<const vfloat4*>(&wt[(F)][4]);         \
    acc[0] += wa.x * (T); acc[1] += wa.y * (T);                                \
    acc[2] += wa.z * (T); acc[3] += wa.w * (T);                                \
    acc[4] += wb.x * (T); acc[5] += wb.y * (T);                                \
    acc[6] += wb.z * (T); acc[7] += wb.w * (T);                                \
} while (0)
#define FENCE() __builtin_amdgcn_sched_barrier(0)

__global__ __launch_bounds__(256, 4) void hoaf_lds(
    const float* __restrict__ x,
    const float* __restrict__ w1, const float* __restrict__ b1,
    const float* __restrict__ w2, const float* __restrict__ b2,
    const float* __restrict__ w3, const float* __restrict__ b3,
    float* __restrict__ out)
{
    __shared__ __align__(16) float wt[165][8];

    const int tid   = threadIdx.x;
    const int g     = blockIdx.x;
    const int b     = blockIdx.y;
    const int chunk = blockIdx.z;

    for (int idx = tid; idx < 165 * 8; idx += 256) {
        const int f = idx >> 3, o = idx & 7;
        const int ch = g * CPG + o;
        float v;
        if (f < 8)        v = w1[ch * CPG + f];
        else if (f < 44)  v = w2[ch * N2 + (f - 8)];
        else if (f < 164) v = w3[ch * N3 + (f - 44)];
        else              v = b1[ch] + b2[ch] + b3[ch];
        wt[f][o] = v;
    }
    __syncthreads();

    const int q = tid + chunk * 256;
    if (q >= HU) return;

    const vfloat4 b_lo = *reinterpret_cast<const vfloat4*>(&wt[164][0]);
    const vfloat4 b_hi = *reinterpret_cast<const vfloat4*>(&wt[164][4]);

    const size_t base = ((size_t)(b * NGRP + g) * CPG) * HW;
    const vfloat4* x4 = (const vfloat4*)(x + base);
    vfloat4*       o4 = (vfloat4*)(out + base);

    vfloat4 xv[CPG];
#pragma unroll
    for (int c = 0; c < CPG; ++c) xv[c] = x4[(size_t)c * HU + q];

    vfloat4 acc[CPG];
    acc[0] = splat4(b_lo.x); acc[1] = splat4(b_lo.y);
    acc[2] = splat4(b_lo.z); acc[3] = splat4(b_lo.w);
    acc[4] = splat4(b_hi.x); acc[5] = splat4(b_hi.y);
    acc[6] = splat4(b_hi.z); acc[7] = splat4(b_hi.w);

#pragma unroll
    for (int k = 0; k < CPG; k += 2) {
        ACCUM(k, xv[k]);
        ACCUM(k + 1, xv[k + 1]);
        FENCE();
    }

#pragma unroll
    for (int i = 0; i < CPG; ++i) {
#pragma unroll
        for (int j = i; j < CPG; ++j) {
            const vfloat4 p = xv[i] * xv[j];
            ACCUM(8 + idx2(i, j), p);
#pragma unroll
            for (int a = 0; a <= i; ++a) {
                const vfloat4 t = xv[a] * p;
                ACCUM(44 + idx3(a, i, j), t);
            }
            FENCE();
        }
    }

#pragma unroll
    for (int o = 0; o < CPG; ++o) o4[(size_t)o * HU + q] = acc[o];
}

extern "C" void kernel_launch(void* const* d_in, const int* in_sizes, int n_in,
                              void* d_out, int out_size, void* d_ws, size_t ws_size,
                              hipStream_t stream) {
    const float* x  = (const float*)d_in[0];
    const float* w1 = (const float*)d_in[1];
    const float* b1 = (const float*)d_in[2];
    const float* w2 = (const float*)d_in[3];
    const float* b2 = (const float*)d_in[4];
    const float* w3 = (const float*)d_in[5];
    const float* b3 = (const float*)d_in[6];
    float* out = (float*)d_out;
    float* ws  = (float*)d_ws;

    dim3 grid(NGRP, NB, 4);   // (group, batch, pixel-chunk) — chunk slowest
    dim3 block(256);

    const size_t ws_needed = (size_t)NGRP * WSTRIDE * sizeof(float);  // 169 KB
    if (ws != nullptr && ws_size >= ws_needed) {
        prep_weights<<<dim3(NGRP), dim3(256), 0, stream>>>(w1, b1, w2, b2, w3, b3, ws);
        hoaf_sload<<<grid, block, 0, stream>>>(x, ws, out);
    } else {
        hoaf_lds<<<grid, block, 0, stream>>>(x, w1, b1, w2, b2, w3, b3, out);
    }
}